// Round 7
// baseline (421.677 us; speedup 1.0000x reference)
//
#include <hip/hip_runtime.h>
#include <hip/hip_bf16.h>
#include <math.h>

#define DIMC  256
#define HEADS 8
#define DH    64
#define INNER 512
#define TOPK  512
#define LQ    16384
#define LKE   4096
#define NB    2
#define NBH   16

typedef __attribute__((ext_vector_type(8))) short bf16x8;
typedef __attribute__((ext_vector_type(4))) float f32x4;

__device__ __forceinline__ unsigned short f2bf(float f) {
    unsigned u = __float_as_uint(f);
    u += 0x7FFFu + ((u >> 16) & 1u);
    return (unsigned short)(u >> 16);
}
__device__ __forceinline__ float bf2f(unsigned short b) {
    return __uint_as_float(((unsigned)b) << 16);
}
__device__ __forceinline__ f32x4 mfma16(bf16x8 a, bf16x8 b, f32x4 c) {
    return __builtin_amdgcn_mfma_f32_16x16x32_bf16(a, b, c, 0, 0, 0);
}
__device__ __forceinline__ unsigned f2q(float v) {   // monotone map [-1,1] -> u32
    return (unsigned)((int)rintf(v * 8388608.0f) + (1 << 24));
}

// ---------------- channel-LN stats: one thread per (b,l) ----------------
__global__ void stats_kernel(const float* __restrict__ x, float* __restrict__ mu,
                             float* __restrict__ rs, int L, int total) {
    int idx = blockIdx.x * 256 + threadIdx.x;
    if (idx >= total) return;
    int b = idx / L, l = idx - b * L;
    const float* p = x + (size_t)b * DIMC * L + l;
    float s = 0.f, sq = 0.f;
    for (int c = 0; c < DIMC; c++) {
        float v = p[(size_t)c * L];
        s += v; sq += v * v;
    }
    float m = s * (1.0f / DIMC);
    float var = fmaxf(sq * (1.0f / DIMC) - m * m, 0.f);
    mu[idx] = m;
    rs[idx] = rsqrtf(var + 1e-5f);
}

// ------- LN + transpose to [b][L][C], bf16 hi (and optional lo) planes -------
template<bool WRITELO>
__global__ __launch_bounds__(256) void ln_transpose_kernel(
    const float* __restrict__ x, const float* __restrict__ mu, const float* __restrict__ rs,
    const float* __restrict__ g, const float* __restrict__ beta, int L,
    unsigned short* __restrict__ xhi, unsigned short* __restrict__ xlo) {
    int lt = blockIdx.x, ct = blockIdx.y, b = blockIdx.z;
    int l0 = lt * 64, c0 = ct * 64;
    int t = threadIdx.x;
    __shared__ float T[64][65];
#pragma unroll
    for (int r = 0; r < 16; r++) {
        int f = r * 256 + t;
        int l = f & 63, c = f >> 6;
        int loc = b * L + l0 + l;
        float v = x[((size_t)b * DIMC + c0 + c) * L + l0 + l];
        T[c][l] = (v - mu[loc]) * rs[loc] * g[c0 + c] + beta[c0 + c];
    }
    __syncthreads();
#pragma unroll
    for (int r = 0; r < 16; r++) {
        int f = r * 256 + t;
        int c = f & 63, l = f >> 6;
        float v = T[c][l];
        unsigned short hi = f2bf(v);
        size_t di = ((size_t)b * L + l0 + l) * DIMC + c0 + c;
        xhi[di] = hi;
        if (WRITELO) xlo[di] = f2bf(v - bf2f(hi));
    }
}

// ------------- MFMA GEMM, 128x128 tile, fused epilogues -------------
// MODE 0: KV proj  (M=1024,K=256,N=LKE)  rows<512 -> kf+kint (L2norm, SPLIT-precision),
//                                        rows>=512 -> vf (single bf16)
// MODE 1: Q  proj  (M=512, K=256,N=LQ)   single bf16, L2norm -> qh bf16
// MODE 2: OUT      (M=256, K=512,N=LQ)   single bf16 -> pre [b][l][256] f32
template<int MODE>
__global__ __launch_bounds__(256) void gemm_mfma_kernel(
    const float* __restrict__ wmat,
    const unsigned short* __restrict__ xhi, const unsigned short* __restrict__ xlo,
    void* __restrict__ dst0, void* __restrict__ dst1, void* __restrict__ dst2) {
    constexpr int K = (MODE == 2) ? 512 : 256;
    constexpr int N = (MODE == 0) ? LKE : LQ;
    constexpr bool MAYSPLIT = (MODE == 0);
    int n0 = blockIdx.x * 128;
    int by = blockIdx.y;
    int bb = blockIdx.z;
    int t = threadIdx.x, w = t >> 6, lane = t & 63;
    int wm = w >> 1, wn = w & 1;
    int lanelo = lane & 15, lanehi = lane >> 4;

    __shared__ __align__(16) char Wh[16384];
    __shared__ __align__(16) char Xh[16384];
    __shared__ __align__(16) char Wl[MAYSPLIT ? 16384 : 16];
    __shared__ __align__(16) char Xl[MAYSPLIT ? 16384 : 16];

    bool split = MAYSPLIT && (by < 4);   // only the K-projection rows need split precision

    const float* wsrc = wmat + (size_t)by * 128 * K;
    const unsigned short* xsh = xhi + ((size_t)bb * N + n0) * K;
    const unsigned short* xsl = xlo + ((size_t)bb * N + n0) * K;

    f32x4 acc[4][4];
#pragma unroll
    for (int mi = 0; mi < 4; mi++)
#pragma unroll
        for (int ni = 0; ni < 4; ni++) acc[mi][ni] = (f32x4){0.f, 0.f, 0.f, 0.f};

    for (int k0 = 0; k0 < K; k0 += 64) {
        if (k0) __syncthreads();
#pragma unroll
        for (int gg = 0; gg < 4; gg++) {
            int e = gg * 2048 + t * 8;
            int row = e >> 6, kc = e & 63;
            const float* wp = wsrc + (size_t)row * K + k0 + kc;
            bf16x8 hi, lo;
#pragma unroll
            for (int i = 0; i < 8; i++) {
                float v = wp[i];
                unsigned short h = f2bf(v);
                hi[i] = (short)h;
                if (MAYSPLIT) lo[i] = (short)f2bf(v - bf2f(h));
            }
            int off = (row * 128 + kc * 2) ^ ((row & 7) << 4);
            *(bf16x8*)(Wh + off) = hi;
            *(bf16x8*)(Xh + off) = *(const bf16x8*)(xsh + (size_t)row * K + k0 + kc);
            if (split) {
                *(bf16x8*)(Wl + off) = lo;
                *(bf16x8*)(Xl + off) = *(const bf16x8*)(xsl + (size_t)row * K + k0 + kc);
            }
        }
        __syncthreads();
#pragma unroll
        for (int kk = 0; kk < 2; kk++) {
            bf16x8 ah[4], bh_[4];
#pragma unroll
            for (int mi = 0; mi < 4; mi++) {
                int row = wm * 64 + mi * 16 + lanelo;
                int off = (row * 128 + kk * 64 + lanehi * 16) ^ ((row & 7) << 4);
                ah[mi] = *(const bf16x8*)(Wh + off);
            }
#pragma unroll
            for (int ni = 0; ni < 4; ni++) {
                int row = wn * 64 + ni * 16 + lanelo;
                int off = (row * 128 + kk * 64 + lanehi * 16) ^ ((row & 7) << 4);
                bh_[ni] = *(const bf16x8*)(Xh + off);
            }
#pragma unroll
            for (int mi = 0; mi < 4; mi++)
#pragma unroll
                for (int ni = 0; ni < 4; ni++)
                    acc[mi][ni] = mfma16(ah[mi], bh_[ni], acc[mi][ni]);
            if (split) {
                bf16x8 al[4], bl_[4];
#pragma unroll
                for (int mi = 0; mi < 4; mi++) {
                    int row = wm * 64 + mi * 16 + lanelo;
                    int off = (row * 128 + kk * 64 + lanehi * 16) ^ ((row & 7) << 4);
                    al[mi] = *(const bf16x8*)(Wl + off);
                }
#pragma unroll
                for (int ni = 0; ni < 4; ni++) {
                    int row = wn * 64 + ni * 16 + lanelo;
                    int off = (row * 128 + kk * 64 + lanehi * 16) ^ ((row & 7) << 4);
                    bl_[ni] = *(const bf16x8*)(Xl + off);
                }
#pragma unroll
                for (int mi = 0; mi < 4; mi++)
#pragma unroll
                    for (int ni = 0; ni < 4; ni++) {
                        acc[mi][ni] = mfma16(ah[mi], bl_[ni], acc[mi][ni]);
                        acc[mi][ni] = mfma16(al[mi], bh_[ni], acc[mi][ni]);
                    }
            }
        }
    }

    // epilogue
    bool donorm = (MODE == 1) || (MODE == 0 && by < 4);
    float inv[4];
    if (donorm) {
#pragma unroll
        for (int ni = 0; ni < 4; ni++) {
            float s = 0.f;
#pragma unroll
            for (int mi = 0; mi < 4; mi++)
#pragma unroll
                for (int rg = 0; rg < 4; rg++) s += acc[mi][ni][rg] * acc[mi][ni][rg];
            s += __shfl_xor(s, 16);
            s += __shfl_xor(s, 32);
            inv[ni] = 1.0f / fmaxf(sqrtf(s), 1e-12f);
        }
    }
#pragma unroll
    for (int mi = 0; mi < 4; mi++) {
        int rowg = by * 128 + wm * 64 + mi * 16 + lanehi * 4;
#pragma unroll
        for (int ni = 0; ni < 4; ni++) {
            int l = n0 + wn * 64 + ni * 16 + lanelo;
            if (MODE == 0) {
                bool isk = rowg < 512;
                float sc = isk ? inv[ni] : 1.0f;
                int h = (rowg >> 6) & 7, d0 = rowg & 63;
                float4 v = make_float4(acc[mi][ni][0] * sc, acc[mi][ni][1] * sc,
                                       acc[mi][ni][2] * sc, acc[mi][ni][3] * sc);
                float* dp = isk ? (float*)dst0 : (float*)dst1;
                size_t base = ((size_t)(bb * HEADS + h) * LKE + l) * 64 + d0;
                *(float4*)&dp[base] = v;
                if (isk) {
                    uint4 ui;
                    ui.x = f2q(v.x); ui.y = f2q(v.y); ui.z = f2q(v.z); ui.w = f2q(v.w);
                    *(uint4*)&((unsigned*)dst2)[base] = ui;
                }
            } else if (MODE == 1) {
                int h = rowg >> 6, d0 = rowg & 63;
                ushort4 u;
                u.x = f2bf(acc[mi][ni][0] * inv[ni]);
                u.y = f2bf(acc[mi][ni][1] * inv[ni]);
                u.z = f2bf(acc[mi][ni][2] * inv[ni]);
                u.w = f2bf(acc[mi][ni][3] * inv[ni]);
                unsigned short* qp = (unsigned short*)dst0;
                *(ushort4*)&qp[((size_t)(bb * HEADS + h) * LQ + l) * 64 + d0] = u;
            } else {
                float4 v = make_float4(acc[mi][ni][0], acc[mi][ni][1],
                                       acc[mi][ni][2], acc[mi][ni][3]);
                float* pp = (float*)dst0;
                *(float4*)&pp[((size_t)bb * LQ + l) * 256 + rowg] = v;
            }
        }
    }
}

// ------- exact f32 sampled-query recompute: LN -> w_q proj -> l2norm -> int ----
__global__ __launch_bounds__(256) void qsample_kernel(
    const float* __restrict__ x, const float* __restrict__ mu, const float* __restrict__ rs,
    const float* __restrict__ g, const float* __restrict__ beta,
    const float* __restrict__ w, const int* __restrict__ ridx,
    unsigned* __restrict__ Qint) {
    int lt = blockIdx.x, bh = blockIdx.y;
    int b = bh >> 3, h = bh & 7;
    int t = threadIdx.x, tx = t & 15, ty = t >> 4;
    __shared__ float Ws[64][33];
    __shared__ float Xs[32][65];
    __shared__ float Cs[64][65];
    __shared__ float nf[64];
    __shared__ int lidx[64];
    if (t < 64) lidx[t] = ridx[bh * TOPK + lt * 64 + t];
    __syncthreads();
    float acc[4][4];
#pragma unroll
    for (int a = 0; a < 4; a++)
#pragma unroll
        for (int c2 = 0; c2 < 4; c2++) acc[a][c2] = 0.f;
    for (int kc = 0; kc < DIMC; kc += 32) {
#pragma unroll
        for (int r = 0; r < 8; r++) {
            int f = r * 256 + t;
            int oi = f >> 5, kj = f & 31;
            Ws[oi][kj] = w[(size_t)(h * 64 + oi) * DIMC + kc + kj];
        }
#pragma unroll
        for (int r = 0; r < 8; r++) {
            int f = r * 256 + t;
            int kj = f >> 6, lj = f & 63;
            int l = lidx[lj];
            int loc = b * LQ + l;
            float v = x[(size_t)b * DIMC * LQ + (size_t)(kc + kj) * LQ + l];
            Xs[kj][lj] = (v - mu[loc]) * rs[loc] * g[kc + kj] + beta[kc + kj];
        }
        __syncthreads();
#pragma unroll
        for (int kj = 0; kj < 32; kj++) {
            float wr[4], xr[4];
#pragma unroll
            for (int a = 0; a < 4; a++) wr[a] = Ws[ty * 4 + a][kj];
#pragma unroll
            for (int c2 = 0; c2 < 4; c2++) xr[c2] = Xs[kj][tx * 4 + c2];
#pragma unroll
            for (int a = 0; a < 4; a++)
#pragma unroll
                for (int c2 = 0; c2 < 4; c2++) acc[a][c2] += wr[a] * xr[c2];
        }
        __syncthreads();
    }
#pragma unroll
    for (int a = 0; a < 4; a++)
#pragma unroll
        for (int c2 = 0; c2 < 4; c2++) Cs[ty * 4 + a][tx * 4 + c2] = acc[a][c2];
    __syncthreads();
    if (t < 64) {
        float sq = 0.f;
        for (int o = 0; o < 64; o++) { float v = Cs[o][t]; sq += v * v; }
        nf[t] = 1.0f / fmaxf(sqrtf(sq), 1e-12f);
    }
    __syncthreads();
#pragma unroll
    for (int r = 0; r < 16; r++) {
        int f = r * 256 + t;
        int d = f & 63, lj = f >> 6;
        Qint[((size_t)bh * TOPK + (size_t)lt * 64 + lj) * 64 + d] = f2q(Cs[d][lj] * nf[lj]);
    }
}

// -------- L1 cdist + min via integer v_sad_u32; 2 keys/lane in VGPRs ----------
// grid (LKE/256, NBH, 4): blockDim 128, q range split in z.
__global__ __launch_bounds__(128, 2) void cdist_sad_kernel(
    const unsigned* __restrict__ kint,  // [BH][LKE][64]
    const unsigned* __restrict__ Qint,  // [BH][TOPK][64]
    unsigned* __restrict__ min_d4) {    // [4][BH][LKE]
    int bh = blockIdx.y;
    int key = blockIdx.x * 256 + threadIdx.x;   // second key = key + 128
    int qz = blockIdx.z;
    const unsigned* kp0 = kint + ((size_t)bh * LKE + key) * 64;
    const unsigned* kp1 = kp0 + 128 * 64;
    unsigned ka[64], kb[64];
#pragma unroll
    for (int d4 = 0; d4 < 16; d4++) {
        uint4 v0 = *(const uint4*)(kp0 + d4 * 4);
        uint4 v1 = *(const uint4*)(kp1 + d4 * 4);
        ka[d4 * 4 + 0] = v0.x; ka[d4 * 4 + 1] = v0.y;
        ka[d4 * 4 + 2] = v0.z; ka[d4 * 4 + 3] = v0.w;
        kb[d4 * 4 + 0] = v1.x; kb[d4 * 4 + 1] = v1.y;
        kb[d4 * 4 + 2] = v1.z; kb[d4 * 4 + 3] = v1.w;
    }
    const unsigned* qrow = Qint + ((size_t)bh * TOPK + qz * (TOPK / 4)) * 64;
    unsigned best0 = 0xFFFFFFFFu, best1 = 0xFFFFFFFFu;
    for (int qi = 0; qi < TOPK / 4; qi++) {
        const unsigned* q = qrow + qi * 64;
        unsigned a0 = 0, a1 = 0, a2 = 0, a3 = 0;
        unsigned b0 = 0, b1 = 0, b2 = 0, b3 = 0;
#pragma unroll
        for (int d = 0; d < 64; d += 4) {
            unsigned q0 = q[d], q1 = q[d + 1], q2 = q[d + 2], q3 = q[d + 3];
            asm("v_sad_u32 %0, %1, %2, %0" : "+v"(a0) : "v"(ka[d + 0]), "s"(q0));
            asm("v_sad_u32 %0, %1, %2, %0" : "+v"(b0) : "v"(kb[d + 0]), "s"(q0));
            asm("v_sad_u32 %0, %1, %2, %0" : "+v"(a1) : "v"(ka[d + 1]), "s"(q1));
            asm("v_sad_u32 %0, %1, %2, %0" : "+v"(b1) : "v"(kb[d + 1]), "s"(q1));
            asm("v_sad_u32 %0, %1, %2, %0" : "+v"(a2) : "v"(ka[d + 2]), "s"(q2));
            asm("v_sad_u32 %0, %1, %2, %0" : "+v"(b2) : "v"(kb[d + 2]), "s"(q2));
            asm("v_sad_u32 %0, %1, %2, %0" : "+v"(a3) : "v"(ka[d + 3]), "s"(q3));
            asm("v_sad_u32 %0, %1, %2, %0" : "+v"(b3) : "v"(kb[d + 3]), "s"(q3));
        }
        unsigned s0 = (a0 + a1) + (a2 + a3);
        unsigned s1 = (b0 + b1) + (b2 + b3);
        best0 = min(best0, s0);
        best1 = min(best1, s1);
    }
    size_t obase = ((size_t)qz * NBH + bh) * LKE;
    min_d4[obase + key] = best0;
    min_d4[obase + key + 128] = best1;
}

// ---------------- radix-select 512 smallest per row (deterministic) ----------
__global__ void select_topk_kernel(const unsigned* __restrict__ min_d4, int* __restrict__ isel) {
    int bh = blockIdx.x;
    int t = threadIdx.x;  // 256
    __shared__ unsigned su[LKE];
    __shared__ int hist[256];
    __shared__ int sb[2];
    for (int i = t; i < LKE; i += 256) {
        unsigned a = min(min_d4[(size_t)bh * LKE + i],
                         min_d4[(size_t)(NBH + bh) * LKE + i]);
        unsigned b = min(min_d4[(size_t)(2 * NBH + bh) * LKE + i],
                         min_d4[(size_t)(3 * NBH + bh) * LKE + i]);
        su[i] = min(a, b);
    }
    unsigned prefix = 0, mask = 0;
    int need = TOPK;
    for (int shift = 24; shift >= 0; shift -= 8) {
        hist[t] = 0;
        __syncthreads();
        for (int i = t; i < LKE; i += 256) {
            unsigned u = su[i];
            if ((u & mask) == prefix) atomicAdd(&hist[(u >> shift) & 255], 1);
        }
        __syncthreads();
        if (t == 0) {
            int c = 0, bsel = 0;
            for (; bsel < 255; bsel++) {
                if (c + hist[bsel] >= need) break;
                c += hist[bsel];
            }
            sb[0] = bsel; sb[1] = need - c;
        }
        __syncthreads();
        prefix |= ((unsigned)sb[0]) << shift;
        mask |= (255u << shift);
        need = sb[1];
        __syncthreads();
    }
    if (t < 64) {
        int pos = 0, eqseen = 0;
        unsigned long long lanem1 = (t == 0) ? 0ull : ((1ull << t) - 1ull);
        for (int i0 = 0; i0 < LKE; i0 += 64) {
            unsigned u = su[i0 + t];
            bool lt = (u < prefix);
            bool eq = (u == prefix);
            unsigned long long be = __ballot(eq);
            int eqbefore = __popcll(be & lanem1);
            bool take = lt || (eq && (eqseen + eqbefore) < need);
            unsigned long long bt = __ballot(take);
            if (take) isel[bh * TOPK + pos + __popcll(bt & lanem1)] = i0 + t;
            pos += __popcll(bt);
            eqseen += __popcll(be);
        }
    }
}

// ---------------- gather selected K (f32 -> bf16, [bh][key][d]) ----------------
__global__ void gather_k_kernel(const float* __restrict__ kf, const int* __restrict__ isel,
                                unsigned short* __restrict__ kselh) {
    int idx = blockIdx.x * 256 + threadIdx.x;
    int d = idx & 63;
    int ti = (idx >> 6) & (TOPK - 1);
    int bh = idx >> 15;
    int row = isel[bh * TOPK + ti];
    kselh[idx] = f2bf(kf[((size_t)bh * LKE + row) * 64 + d]);
}

// ---------------- gather selected V transposed (f32 -> bf16, [bh][d][key]) ------
__global__ __launch_bounds__(256) void gather_vT_kernel(
    const float* __restrict__ vf, const int* __restrict__ isel,
    unsigned short* __restrict__ vTh) {
    int bh = blockIdx.y, kc = blockIdx.x * 64;
    int t = threadIdx.x;
    __shared__ float T[64][65];
#pragma unroll
    for (int r = 0; r < 4; r++) {
        int c = r * 256 + t;          // 1024 float4 chunks
        int row = c >> 4, c4 = c & 15;
        int krow = isel[bh * TOPK + kc + row];
        float4 v = *(const float4*)(vf + ((size_t)bh * LKE + krow) * 64 + c4 * 4);
        T[row][c4 * 4 + 0] = v.x; T[row][c4 * 4 + 1] = v.y;
        T[row][c4 * 4 + 2] = v.z; T[row][c4 * 4 + 3] = v.w;
    }
    __syncthreads();
#pragma unroll
    for (int r = 0; r < 16; r++) {
        int f = r * 256 + t;
        int d = f >> 6, key = f & 63;
        vTh[(size_t)bh * 64 * TOPK + (size_t)d * TOPK + kc + key] = f2bf(T[key][d]);
    }
}

// ---------------- MFMA flash attention (single-bf16 P,V; f32 accum) ------------
// scores bounded in [-1,1] (q,k L2-normalized) -> no max subtraction needed.
__global__ __launch_bounds__(256) void attn_mfma_kernel(
    const unsigned short* __restrict__ qh,    // [BH][LQ][64] bf16
    const unsigned short* __restrict__ kselh, // [BH][512][64] bf16
    const unsigned short* __restrict__ vTh,   // [BH][64][512] bf16
    unsigned short* __restrict__ afT) {       // [b][LQ][512] bf16
    int bh = blockIdx.y, rt = blockIdx.x;
    int bq = bh >> 3, h = bh & 7;
    int t = threadIdx.x, w = t >> 6, lane = t & 63;
    __shared__ unsigned short Qs[64 * 64];
    __shared__ unsigned short Ks[64 * 64];
    __shared__ unsigned short Vts[64 * 64];
    __shared__ unsigned short Ps[4 * 16 * 64];

    const unsigned short* qb = qh + ((size_t)bh * LQ + (size_t)rt * 64) * 64;
    const unsigned short* kb = kselh + (size_t)bh * TOPK * 64;
    const unsigned short* vb = vTh + (size_t)bh * 64 * TOPK;

#pragma unroll
    for (int r = 0; r < 2; r++) {
        int c = r * 256 + t; int row = c >> 3, c8 = c & 7;
        bf16x8 v = *(const bf16x8*)(qb + row * 64 + c8 * 8);
        *(bf16x8*)((char*)Qs + ((row * 128 + c8 * 16) ^ ((row & 7) << 4))) = v;
    }
    auto stageKV = [&](int kc0) {
#pragma unroll
        for (int r = 0; r < 2; r++) {
            int c = r * 256 + t; int row = c >> 3, c8 = c & 7;
            int off = (row * 128 + c8 * 16) ^ ((row & 7) << 4);
            *(bf16x8*)((char*)Ks + off) = *(const bf16x8*)(kb + (kc0 + row) * 64 + c8 * 8);
            *(bf16x8*)((char*)Vts + off) = *(const bf16x8*)(vb + row * TOPK + kc0 + c8 * 8);
        }
    };
    stageKV(0);
    __syncthreads();

    bf16x8 qfrag[2];
#pragma unroll
    for (int kk = 0; kk < 2; kk++) {
        int row = w * 16 + (lane & 15);
        qfrag[kk] = *(const bf16x8*)((char*)Qs +
            ((row * 128 + kk * 64 + (lane >> 4) * 16) ^ ((row & 7) << 4)));
    }

    f32x4 o[4];
#pragma unroll
    for (int m = 0; m < 4; m++) o[m] = (f32x4){0.f, 0.f, 0.f, 0.f};
    float lsum[4] = {0.f, 0.f, 0.f, 0.f};
    unsigned short* pw = Ps + w * 16 * 64;

    for (int ch = 0; ch < 8; ch++) {
        f32x4 s[4];
#pragma unroll
        for (int n = 0; n < 4; n++) {
            s[n] = (f32x4){0.f, 0.f, 0.f, 0.f};
#pragma unroll
            for (int kk = 0; kk < 2; kk++) {
                int row = n * 16 + (lane & 15);
                bf16x8 kfr = *(const bf16x8*)((char*)Ks +
                    ((row * 128 + kk * 64 + (lane >> 4) * 16) ^ ((row & 7) << 4)));
                s[n] = mfma16(qfrag[kk], kfr, s[n]);
            }
        }
        float part[4] = {0.f, 0.f, 0.f, 0.f};
#pragma unroll
        for (int n = 0; n < 4; n++) {
#pragma unroll
            for (int rg = 0; rg < 4; rg++) {
                float p = __expf(s[n][rg]);
                part[rg] += p;
                int row = (lane >> 4) * 4 + rg, col = n * 16 + (lane & 15);
                *(unsigned short*)((char*)pw +
                    ((row * 128 + col * 2) ^ ((row & 7) << 4))) = f2bf(p);
            }
        }
#pragma unroll
        for (int rg = 0; rg < 4; rg++) {
            float v = part[rg];
            v += __shfl_xor(v, 1); v += __shfl_xor(v, 2);
            v += __shfl_xor(v, 4); v += __shfl_xor(v, 8);
            lsum[rg] += v;
        }
        bf16x8 pfrag[2];
#pragma unroll
        for (int kk = 0; kk < 2; kk++) {
            int row = lane & 15;
            pfrag[kk] = *(const bf16x8*)((char*)pw +
                ((row * 128 + kk * 64 + (lane >> 4) * 16) ^ ((row & 7) << 4)));
        }
#pragma unroll
        for (int m = 0; m < 4; m++) {
#pragma unroll
            for (int kk = 0; kk < 2; kk++) {
                int row = m * 16 + (lane & 15);
                bf16x8 vfr = *(const bf16x8*)((char*)Vts +
                    ((row * 128 + kk * 64 + (lane >> 4) * 16) ^ ((row & 7) << 4)));
                o[m] = mfma16(pfrag[kk], vfr, o[m]);
            }
        }
        if (ch < 7) {
            __syncthreads();
            stageKV((ch + 1) * 64);
            __syncthreads();
        }
    }
    int row0 = w * 16 + (lane >> 4) * 4;
#pragma unroll
    for (int rg = 0; rg < 4; rg++) {
        float invs = 1.0f / lsum[rg];
        int l = rt * 64 + row0 + rg;
        size_t base = ((size_t)bq * LQ + l) * 512 + h * 64 + (lane & 15);
#pragma unroll
        for (int m = 0; m < 4; m++)
            afT[base + m * 16] = f2bf(o[m][rg] * invs);
    }
}

// ---------------- per-location stats over 256 channels (pre is [b][l][256]) ----
__global__ void stats_loc_kernel(const float* __restrict__ pre, float* __restrict__ mu,
                                 float* __restrict__ rs) {
    int t = threadIdx.x;
    int grp = t >> 4, ln = t & 15;
    int loc = blockIdx.x * 16 + grp;
    const float4* p = (const float4*)(pre + (size_t)loc * 256);
    float s = 0.f, sq = 0.f;
#pragma unroll
    for (int i = 0; i < 4; i++) {
        float4 v = p[ln + i * 16];
        s += v.x + v.y + v.z + v.w;
        sq += v.x * v.x + v.y * v.y + v.z * v.z + v.w * v.w;
    }
#pragma unroll
    for (int d = 1; d < 16; d <<= 1) {
        s += __shfl_xor(s, d);
        sq += __shfl_xor(sq, d);
    }
    if (ln == 0) {
        float m = s * (1.0f / 256.0f);
        float var = fmaxf(sq * (1.0f / 256.0f) - m * m, 0.f);
        mu[loc] = m;
        rs[loc] = rsqrtf(var + 1e-5f);
    }
}

// ---------------- final LN + gamma*x + residual (transpose to [b][ch][l]) ------
__global__ __launch_bounds__(256) void final_kernel(
    const float* __restrict__ pre, const float* __restrict__ mu,
    const float* __restrict__ rs, const float* __restrict__ g,
    const float* __restrict__ beta, const float* __restrict__ gamma,
    const float* __restrict__ qs_in, float* __restrict__ out) {
    int lt = blockIdx.x, ot = blockIdx.y, b = blockIdx.z;
    int l0 = lt * 64, o0 = ot * 64;
    int t = threadIdx.x;
    __shared__ float T[64][65];
    float gm = gamma[0];
#pragma unroll
    for (int r = 0; r < 16; r++) {
        int f = r * 256 + t;
        int o = f & 63, l = f >> 6;
        int loc = b * LQ + l0 + l;
        float v = pre[(size_t)loc * 256 + o0 + o];
        T[o][l] = ((v - mu[loc]) * rs[loc] * g[o0 + o] + beta[o0 + o]) * gm;
    }
    __syncthreads();
#pragma unroll
    for (int r = 0; r < 16; r++) {
        int f = r * 256 + t;
        int l = f & 63, o = f >> 6;
        size_t oi = ((size_t)(b * DIMC + o0 + o)) * LQ + l0 + l;
        out[oi] = T[o][l] + qs_in[oi];
    }
}

extern "C" void kernel_launch(void* const* d_in, const int* in_sizes, int n_in,
                              void* d_out, int out_size, void* d_ws, size_t ws_size,
                              hipStream_t stream) {
    const float* qs_in = (const float*)d_in[0];
    const float* ctx   = (const float*)d_in[1];
    const int*   ridx  = (const int*)d_in[2];
    const float* g_ctx = (const float*)d_in[3];
    const float* b_ctx = (const float*)d_in[4];
    const float* g_qs  = (const float*)d_in[5];
    const float* b_qs  = (const float*)d_in[6];
    const float* w_kv  = (const float*)d_in[7];
    const float* w_q   = (const float*)d_in[8];
    const float* w_out = (const float*)d_in[9];
    const float* g_out = (const float*)d_in[10];
    const float* b_out = (const float*)d_in[11];
    const float* gamma = (const float*)d_in[12];
    float* out = (float*)d_out;

    char* ws = (char*)d_ws;
    size_t off = 0;
    auto alloc = [&](size_t bytes) { char* p = ws + off; off += (bytes + 255) & ~(size_t)255; return p; };

    float*          kf    = (float*)alloc((size_t)NBH * LKE * 64 * 4);
    float*          vf    = (float*)alloc((size_t)NBH * LKE * 64 * 4);
    unsigned*       kint  = (unsigned*)alloc((size_t)NBH * LKE * 64 * 4);
    unsigned short* qh    = (unsigned short*)alloc((size_t)NBH * LQ * 64 * 2);
    // union region: {ctxT_hi, ctxT_lo, qsT_hi} (early) / {afT} (late, after gemm<1>)
    char*           uni   = alloc((size_t)NB * LQ * INNER * 2);   // 33.6 MB
    unsigned short* ctxT_hi = (unsigned short*)(uni);
    unsigned short* ctxT_lo = (unsigned short*)(uni + (size_t)NB * LKE * DIMC * 2);
    unsigned short* qsT_hi  = (unsigned short*)(uni + (size_t)2 * NB * LKE * DIMC * 2);
    unsigned short* afT     = (unsigned short*)(uni);

    unsigned*       Qint  = (unsigned*)alloc((size_t)NBH * TOPK * 64 * 4);
    unsigned short* kselh = (unsigned short*)alloc((size_t)NBH * TOPK * 64 * 2);
    unsigned short* vTh   = (unsigned short*)alloc((size_t)NBH * 64 * TOPK * 2);
    float*          pre   = (float*)alloc((size_t)NB * LQ * DIMC * 4);
    unsigned*       min_d4= (unsigned*)alloc((size_t)4 * NBH * LKE * 4);
    float*          mu_c  = (float*)alloc(NB * LKE * 4);
    float*          rs_c  = (float*)alloc(NB * LKE * 4);
    float*          mu_q  = (float*)alloc(NB * LQ * 4);
    float*          rs_q  = (float*)alloc(NB * LQ * 4);
    float*          mu_o  = (float*)alloc(NB * LQ * 4);
    float*          rs_o  = (float*)alloc(NB * LQ * 4);
    int*            isel  = (int*)alloc(NBH * TOPK * 4);

    stats_kernel<<<(NB * LKE + 255) / 256, 256, 0, stream>>>(ctx, mu_c, rs_c, LKE, NB * LKE);
    stats_kernel<<<(NB * LQ + 255) / 256, 256, 0, stream>>>(qs_in, mu_q, rs_q, LQ, NB * LQ);
    ln_transpose_kernel<true><<<dim3(LKE / 64, DIMC / 64, NB), 256, 0, stream>>>(
        ctx, mu_c, rs_c, g_ctx, b_ctx, LKE, ctxT_hi, ctxT_lo);
    ln_transpose_kernel<false><<<dim3(LQ / 64, DIMC / 64, NB), 256, 0, stream>>>(
        qs_in, mu_q, rs_q, g_qs, b_qs, LQ, qsT_hi, nullptr);
    gemm_mfma_kernel<0><<<dim3(LKE / 128, 8, NB), 256, 0, stream>>>(
        w_kv, ctxT_hi, ctxT_lo, kf, vf, kint);
    gemm_mfma_kernel<1><<<dim3(LQ / 128, 4, NB), 256, 0, stream>>>(
        w_q, qsT_hi, qsT_hi, qh, nullptr, nullptr);
    qsample_kernel<<<dim3(TOPK / 64, NBH), 256, 0, stream>>>(
        qs_in, mu_q, rs_q, g_qs, b_qs, w_q, ridx, Qint);
    cdist_sad_kernel<<<dim3(LKE / 256, NBH, 4), 128, 0, stream>>>(kint, Qint, min_d4);
    select_topk_kernel<<<NBH, 256, 0, stream>>>(min_d4, isel);
    gather_k_kernel<<<(NBH * TOPK * 64) / 256, 256, 0, stream>>>(kf, isel, kselh);
    gather_vT_kernel<<<dim3(TOPK / 64, NBH), 256, 0, stream>>>(vf, isel, vTh);
    attn_mfma_kernel<<<dim3(LQ / 64, NBH), 256, 0, stream>>>(qh, kselh, vTh, afT);
    gemm_mfma_kernel<2><<<dim3(LQ / 128, 2, NB), 256, 0, stream>>>(
        w_out, afT, afT, pre, nullptr, nullptr);
    stats_loc_kernel<<<(NB * LQ) / 16, 256, 0, stream>>>(pre, mu_o, rs_o);
    final_kernel<<<dim3(LQ / 64, DIMC / 64, NB), 256, 0, stream>>>(
        pre, mu_o, rs_o, g_out, b_out, gamma, qs_in, out);
}

// Round 8
// 401.043 us; speedup vs baseline: 1.0515x; 1.0515x over previous
//
#include <hip/hip_runtime.h>
#include <hip/hip_bf16.h>
#include <math.h>

#define DIMC  256
#define HEADS 8
#define DH    64
#define INNER 512
#define TOPK  512
#define LQ    16384
#define LKE   4096
#define NB    2
#define NBH   16

typedef __attribute__((ext_vector_type(8))) short bf16x8;
typedef __attribute__((ext_vector_type(4))) float f32x4;

__device__ __forceinline__ unsigned short f2bf(float f) {
    unsigned u = __float_as_uint(f);
    u += 0x7FFFu + ((u >> 16) & 1u);
    return (unsigned short)(u >> 16);
}
__device__ __forceinline__ float bf2f(unsigned short b) {
    return __uint_as_float(((unsigned)b) << 16);
}
__device__ __forceinline__ f32x4 mfma16(bf16x8 a, bf16x8 b, f32x4 c) {
    return __builtin_amdgcn_mfma_f32_16x16x32_bf16(a, b, c, 0, 0, 0);
}
__device__ __forceinline__ unsigned f2q(float v) {   // monotone map [-1,1] -> u32
    return (unsigned)((int)rintf(v * 8388608.0f) + (1 << 24));
}

// ---------------- channel-LN stats: one thread per (b,l) ----------------
__global__ void stats_kernel(const float* __restrict__ x, float* __restrict__ mu,
                             float* __restrict__ rs, int L, int total) {
    int idx = blockIdx.x * 256 + threadIdx.x;
    if (idx >= total) return;
    int b = idx / L, l = idx - b * L;
    const float* p = x + (size_t)b * DIMC * L + l;
    float s = 0.f, sq = 0.f;
    for (int c = 0; c < DIMC; c++) {
        float v = p[(size_t)c * L];
        s += v; sq += v * v;
    }
    float m = s * (1.0f / DIMC);
    float var = fmaxf(sq * (1.0f / DIMC) - m * m, 0.f);
    mu[idx] = m;
    rs[idx] = rsqrtf(var + 1e-5f);
}

// ------- LN + transpose to [b][L][C], bf16 hi (and optional lo) planes -------
template<bool WRITELO>
__global__ __launch_bounds__(256) void ln_transpose_kernel(
    const float* __restrict__ x, const float* __restrict__ mu, const float* __restrict__ rs,
    const float* __restrict__ g, const float* __restrict__ beta, int L,
    unsigned short* __restrict__ xhi, unsigned short* __restrict__ xlo) {
    int lt = blockIdx.x, ct = blockIdx.y, b = blockIdx.z;
    int l0 = lt * 64, c0 = ct * 64;
    int t = threadIdx.x;
    __shared__ float T[64][65];
#pragma unroll
    for (int r = 0; r < 16; r++) {
        int f = r * 256 + t;
        int l = f & 63, c = f >> 6;
        int loc = b * L + l0 + l;
        float v = x[((size_t)b * DIMC + c0 + c) * L + l0 + l];
        T[c][l] = (v - mu[loc]) * rs[loc] * g[c0 + c] + beta[c0 + c];
    }
    __syncthreads();
#pragma unroll
    for (int r = 0; r < 16; r++) {
        int f = r * 256 + t;
        int c = f & 63, l = f >> 6;
        float v = T[c][l];
        unsigned short hi = f2bf(v);
        size_t di = ((size_t)b * L + l0 + l) * DIMC + c0 + c;
        xhi[di] = hi;
        if (WRITELO) xlo[di] = f2bf(v - bf2f(hi));
    }
}

// ------------- MFMA GEMM, 128x128 tile, fused epilogues -------------
// MODE 0: KV proj  (M=1024,K=256,N=LKE)  rows<512 -> kf+kint (L2norm, SPLIT-precision),
//                                        rows>=512 -> vf (single bf16)
// MODE 1: Q  proj  (M=512, K=256,N=LQ)   single bf16, L2norm -> qh bf16
// MODE 2: OUT      (M=256, K=512,N=LQ)   single bf16 -> pre [b][l][256] f32
template<int MODE>
__global__ __launch_bounds__(256) void gemm_mfma_kernel(
    const float* __restrict__ wmat,
    const unsigned short* __restrict__ xhi, const unsigned short* __restrict__ xlo,
    void* __restrict__ dst0, void* __restrict__ dst1, void* __restrict__ dst2) {
    constexpr int K = (MODE == 2) ? 512 : 256;
    constexpr int N = (MODE == 0) ? LKE : LQ;
    constexpr bool MAYSPLIT = (MODE == 0);
    int n0 = blockIdx.x * 128;
    int by = blockIdx.y;
    int bb = blockIdx.z;
    int t = threadIdx.x, w = t >> 6, lane = t & 63;
    int wm = w >> 1, wn = w & 1;
    int lanelo = lane & 15, lanehi = lane >> 4;

    __shared__ __align__(16) char Wh[16384];
    __shared__ __align__(16) char Xh[16384];
    __shared__ __align__(16) char Wl[MAYSPLIT ? 16384 : 16];
    __shared__ __align__(16) char Xl[MAYSPLIT ? 16384 : 16];

    bool split = MAYSPLIT && (by < 4);   // only the K-projection rows need split precision

    const float* wsrc = wmat + (size_t)by * 128 * K;
    const unsigned short* xsh = xhi + ((size_t)bb * N + n0) * K;
    const unsigned short* xsl = xlo + ((size_t)bb * N + n0) * K;

    f32x4 acc[4][4];
#pragma unroll
    for (int mi = 0; mi < 4; mi++)
#pragma unroll
        for (int ni = 0; ni < 4; ni++) acc[mi][ni] = (f32x4){0.f, 0.f, 0.f, 0.f};

    for (int k0 = 0; k0 < K; k0 += 64) {
        if (k0) __syncthreads();
#pragma unroll
        for (int gg = 0; gg < 4; gg++) {
            int e = gg * 2048 + t * 8;
            int row = e >> 6, kc = e & 63;
            const float* wp = wsrc + (size_t)row * K + k0 + kc;
            bf16x8 hi, lo;
#pragma unroll
            for (int i = 0; i < 8; i++) {
                float v = wp[i];
                unsigned short h = f2bf(v);
                hi[i] = (short)h;
                if (MAYSPLIT) lo[i] = (short)f2bf(v - bf2f(h));
            }
            int off = (row * 128 + kc * 2) ^ ((row & 7) << 4);
            *(bf16x8*)(Wh + off) = hi;
            *(bf16x8*)(Xh + off) = *(const bf16x8*)(xsh + (size_t)row * K + k0 + kc);
            if (split) {
                *(bf16x8*)(Wl + off) = lo;
                *(bf16x8*)(Xl + off) = *(const bf16x8*)(xsl + (size_t)row * K + k0 + kc);
            }
        }
        __syncthreads();
#pragma unroll
        for (int kk = 0; kk < 2; kk++) {
            bf16x8 ah[4], bh_[4];
#pragma unroll
            for (int mi = 0; mi < 4; mi++) {
                int row = wm * 64 + mi * 16 + lanelo;
                int off = (row * 128 + kk * 64 + lanehi * 16) ^ ((row & 7) << 4);
                ah[mi] = *(const bf16x8*)(Wh + off);
            }
#pragma unroll
            for (int ni = 0; ni < 4; ni++) {
                int row = wn * 64 + ni * 16 + lanelo;
                int off = (row * 128 + kk * 64 + lanehi * 16) ^ ((row & 7) << 4);
                bh_[ni] = *(const bf16x8*)(Xh + off);
            }
#pragma unroll
            for (int mi = 0; mi < 4; mi++)
#pragma unroll
                for (int ni = 0; ni < 4; ni++)
                    acc[mi][ni] = mfma16(ah[mi], bh_[ni], acc[mi][ni]);
            if (split) {
                bf16x8 al[4], bl_[4];
#pragma unroll
                for (int mi = 0; mi < 4; mi++) {
                    int row = wm * 64 + mi * 16 + lanelo;
                    int off = (row * 128 + kk * 64 + lanehi * 16) ^ ((row & 7) << 4);
                    al[mi] = *(const bf16x8*)(Wl + off);
                }
#pragma unroll
                for (int ni = 0; ni < 4; ni++) {
                    int row = wn * 64 + ni * 16 + lanelo;
                    int off = (row * 128 + kk * 64 + lanehi * 16) ^ ((row & 7) << 4);
                    bl_[ni] = *(const bf16x8*)(Xl + off);
                }
#pragma unroll
                for (int mi = 0; mi < 4; mi++)
#pragma unroll
                    for (int ni = 0; ni < 4; ni++) {
                        acc[mi][ni] = mfma16(ah[mi], bl_[ni], acc[mi][ni]);
                        acc[mi][ni] = mfma16(al[mi], bh_[ni], acc[mi][ni]);
                    }
            }
        }
    }

    // epilogue
    bool donorm = (MODE == 1) || (MODE == 0 && by < 4);
    float inv[4];
    if (donorm) {
#pragma unroll
        for (int ni = 0; ni < 4; ni++) {
            float s = 0.f;
#pragma unroll
            for (int mi = 0; mi < 4; mi++)
#pragma unroll
                for (int rg = 0; rg < 4; rg++) s += acc[mi][ni][rg] * acc[mi][ni][rg];
            s += __shfl_xor(s, 16);
            s += __shfl_xor(s, 32);
            inv[ni] = 1.0f / fmaxf(sqrtf(s), 1e-12f);
        }
    }
#pragma unroll
    for (int mi = 0; mi < 4; mi++) {
        int rowg = by * 128 + wm * 64 + mi * 16 + lanehi * 4;
#pragma unroll
        for (int ni = 0; ni < 4; ni++) {
            int l = n0 + wn * 64 + ni * 16 + lanelo;
            if (MODE == 0) {
                bool isk = rowg < 512;
                float sc = isk ? inv[ni] : 1.0f;
                int h = (rowg >> 6) & 7, d0 = rowg & 63;
                float4 v = make_float4(acc[mi][ni][0] * sc, acc[mi][ni][1] * sc,
                                       acc[mi][ni][2] * sc, acc[mi][ni][3] * sc);
                float* dp = isk ? (float*)dst0 : (float*)dst1;
                size_t base = ((size_t)(bb * HEADS + h) * LKE + l) * 64 + d0;
                *(float4*)&dp[base] = v;
                if (isk) {
                    uint4 ui;
                    ui.x = f2q(v.x); ui.y = f2q(v.y); ui.z = f2q(v.z); ui.w = f2q(v.w);
                    *(uint4*)&((unsigned*)dst2)[base] = ui;
                }
            } else if (MODE == 1) {
                int h = rowg >> 6, d0 = rowg & 63;
                ushort4 u;
                u.x = f2bf(acc[mi][ni][0] * inv[ni]);
                u.y = f2bf(acc[mi][ni][1] * inv[ni]);
                u.z = f2bf(acc[mi][ni][2] * inv[ni]);
                u.w = f2bf(acc[mi][ni][3] * inv[ni]);
                unsigned short* qp = (unsigned short*)dst0;
                *(ushort4*)&qp[((size_t)(bb * HEADS + h) * LQ + l) * 64 + d0] = u;
            } else {
                float4 v = make_float4(acc[mi][ni][0], acc[mi][ni][1],
                                       acc[mi][ni][2], acc[mi][ni][3]);
                float* pp = (float*)dst0;
                *(float4*)&pp[((size_t)bb * LQ + l) * 256 + rowg] = v;
            }
        }
    }
}

// ------- exact f32 sampled-query recompute: LN -> w_q proj -> l2norm -> int ----
__global__ __launch_bounds__(256) void qsample_kernel(
    const float* __restrict__ x, const float* __restrict__ mu, const float* __restrict__ rs,
    const float* __restrict__ g, const float* __restrict__ beta,
    const float* __restrict__ w, const int* __restrict__ ridx,
    unsigned* __restrict__ Qint) {
    int lt = blockIdx.x, bh = blockIdx.y;
    int b = bh >> 3, h = bh & 7;
    int t = threadIdx.x, tx = t & 15, ty = t >> 4;
    __shared__ float Ws[64][33];
    __shared__ float Xs[32][65];
    __shared__ float Cs[64][65];
    __shared__ float nf[64];
    __shared__ int lidx[64];
    if (t < 64) lidx[t] = ridx[bh * TOPK + lt * 64 + t];
    __syncthreads();
    float acc[4][4];
#pragma unroll
    for (int a = 0; a < 4; a++)
#pragma unroll
        for (int c2 = 0; c2 < 4; c2++) acc[a][c2] = 0.f;
    for (int kc = 0; kc < DIMC; kc += 32) {
#pragma unroll
        for (int r = 0; r < 8; r++) {
            int f = r * 256 + t;
            int oi = f >> 5, kj = f & 31;
            Ws[oi][kj] = w[(size_t)(h * 64 + oi) * DIMC + kc + kj];
        }
#pragma unroll
        for (int r = 0; r < 8; r++) {
            int f = r * 256 + t;
            int kj = f >> 6, lj = f & 63;
            int l = lidx[lj];
            int loc = b * LQ + l;
            float v = x[(size_t)b * DIMC * LQ + (size_t)(kc + kj) * LQ + l];
            Xs[kj][lj] = (v - mu[loc]) * rs[loc] * g[kc + kj] + beta[kc + kj];
        }
        __syncthreads();
#pragma unroll
        for (int kj = 0; kj < 32; kj++) {
            float wr[4], xr[4];
#pragma unroll
            for (int a = 0; a < 4; a++) wr[a] = Ws[ty * 4 + a][kj];
#pragma unroll
            for (int c2 = 0; c2 < 4; c2++) xr[c2] = Xs[kj][tx * 4 + c2];
#pragma unroll
            for (int a = 0; a < 4; a++)
#pragma unroll
                for (int c2 = 0; c2 < 4; c2++) acc[a][c2] += wr[a] * xr[c2];
        }
        __syncthreads();
    }
#pragma unroll
    for (int a = 0; a < 4; a++)
#pragma unroll
        for (int c2 = 0; c2 < 4; c2++) Cs[ty * 4 + a][tx * 4 + c2] = acc[a][c2];
    __syncthreads();
    if (t < 64) {
        float sq = 0.f;
        for (int o = 0; o < 64; o++) { float v = Cs[o][t]; sq += v * v; }
        nf[t] = 1.0f / fmaxf(sqrtf(sq), 1e-12f);
    }
    __syncthreads();
#pragma unroll
    for (int r = 0; r < 16; r++) {
        int f = r * 256 + t;
        int d = f & 63, lj = f >> 6;
        Qint[((size_t)bh * TOPK + (size_t)lt * 64 + lj) * 64 + d] = f2q(Cs[d][lj] * nf[lj]);
    }
}

// -------- L1 cdist + min via integer v_sad_u32; K pinned in VGPRs --------------
// grid (LKE/256, NBH, 4): blockDim 256, 1 key/lane, q range split in z.
// waves_per_eu(4,4): pins occupancy so the scheduler keeps k[64] resident.
__global__ __launch_bounds__(256) __attribute__((amdgpu_waves_per_eu(4, 4)))
void cdist_sad_kernel(
    const unsigned* __restrict__ kint,  // [BH][LKE][64]
    const unsigned* __restrict__ Qint,  // [BH][TOPK][64]
    unsigned* __restrict__ min_d4) {    // [4][BH][LKE]
    int bh = blockIdx.y;
    int key = blockIdx.x * 256 + threadIdx.x;
    int qz = blockIdx.z;
    const unsigned* kp = kint + ((size_t)bh * LKE + key) * 64;
    unsigned k[64];
#pragma unroll
    for (int d4 = 0; d4 < 16; d4++) {
        uint4 v = *(const uint4*)(kp + d4 * 4);
        k[d4 * 4 + 0] = v.x; k[d4 * 4 + 1] = v.y;
        k[d4 * 4 + 2] = v.z; k[d4 * 4 + 3] = v.w;
    }
    // opaque tie: force all 64 values to live VGPRs; loads cannot be sunk/remat'd
#pragma unroll
    for (int d = 0; d < 64; d++) asm volatile("" : "+v"(k[d]));

    const unsigned* qrow = Qint + ((size_t)bh * TOPK + qz * (TOPK / 4)) * 64;
    unsigned best = 0xFFFFFFFFu;
    for (int qi = 0; qi < TOPK / 4; qi++) {
        const unsigned* q = qrow + qi * 64;
        unsigned a0 = 0, a1 = 0, a2 = 0, a3 = 0;
#pragma unroll
        for (int d = 0; d < 64; d += 4) {
            unsigned q0 = q[d], q1 = q[d + 1], q2 = q[d + 2], q3 = q[d + 3];
            asm("v_sad_u32 %0, %1, %2, %0" : "+v"(a0) : "v"(k[d + 0]), "s"(q0));
            asm("v_sad_u32 %0, %1, %2, %0" : "+v"(a1) : "v"(k[d + 1]), "s"(q1));
            asm("v_sad_u32 %0, %1, %2, %0" : "+v"(a2) : "v"(k[d + 2]), "s"(q2));
            asm("v_sad_u32 %0, %1, %2, %0" : "+v"(a3) : "v"(k[d + 3]), "s"(q3));
        }
        unsigned s = (a0 + a1) + (a2 + a3);
        best = min(best, s);
    }
    min_d4[((size_t)qz * NBH + bh) * LKE + key] = best;
}

// ---------------- radix-select 512 smallest per row (deterministic) ----------
__global__ void select_topk_kernel(const unsigned* __restrict__ min_d4, int* __restrict__ isel) {
    int bh = blockIdx.x;
    int t = threadIdx.x;  // 256
    __shared__ unsigned su[LKE];
    __shared__ int hist[256];
    __shared__ int sb[2];
    for (int i = t; i < LKE; i += 256) {
        unsigned a = min(min_d4[(size_t)bh * LKE + i],
                         min_d4[(size_t)(NBH + bh) * LKE + i]);
        unsigned b = min(min_d4[(size_t)(2 * NBH + bh) * LKE + i],
                         min_d4[(size_t)(3 * NBH + bh) * LKE + i]);
        su[i] = min(a, b);
    }
    unsigned prefix = 0, mask = 0;
    int need = TOPK;
    for (int shift = 24; shift >= 0; shift -= 8) {
        hist[t] = 0;
        __syncthreads();
        for (int i = t; i < LKE; i += 256) {
            unsigned u = su[i];
            if ((u & mask) == prefix) atomicAdd(&hist[(u >> shift) & 255], 1);
        }
        __syncthreads();
        if (t == 0) {
            int c = 0, bsel = 0;
            for (; bsel < 255; bsel++) {
                if (c + hist[bsel] >= need) break;
                c += hist[bsel];
            }
            sb[0] = bsel; sb[1] = need - c;
        }
        __syncthreads();
        prefix |= ((unsigned)sb[0]) << shift;
        mask |= (255u << shift);
        need = sb[1];
        __syncthreads();
    }
    if (t < 64) {
        int pos = 0, eqseen = 0;
        unsigned long long lanem1 = (t == 0) ? 0ull : ((1ull << t) - 1ull);
        for (int i0 = 0; i0 < LKE; i0 += 64) {
            unsigned u = su[i0 + t];
            bool lt = (u < prefix);
            bool eq = (u == prefix);
            unsigned long long be = __ballot(eq);
            int eqbefore = __popcll(be & lanem1);
            bool take = lt || (eq && (eqseen + eqbefore) < need);
            unsigned long long bt = __ballot(take);
            if (take) isel[bh * TOPK + pos + __popcll(bt & lanem1)] = i0 + t;
            pos += __popcll(bt);
            eqseen += __popcll(be);
        }
    }
}

// ---------------- gather selected K (f32 -> bf16, [bh][key][d]) ----------------
__global__ void gather_k_kernel(const float* __restrict__ kf, const int* __restrict__ isel,
                                unsigned short* __restrict__ kselh) {
    int idx = blockIdx.x * 256 + threadIdx.x;
    int d = idx & 63;
    int ti = (idx >> 6) & (TOPK - 1);
    int bh = idx >> 15;
    int row = isel[bh * TOPK + ti];
    kselh[idx] = f2bf(kf[((size_t)bh * LKE + row) * 64 + d]);
}

// ---------------- gather selected V transposed (f32 -> bf16, [bh][d][key]) ------
__global__ __launch_bounds__(256) void gather_vT_kernel(
    const float* __restrict__ vf, const int* __restrict__ isel,
    unsigned short* __restrict__ vTh) {
    int bh = blockIdx.y, kc = blockIdx.x * 64;
    int t = threadIdx.x;
    __shared__ float T[64][65];
#pragma unroll
    for (int r = 0; r < 4; r++) {
        int c = r * 256 + t;          // 1024 float4 chunks
        int row = c >> 4, c4 = c & 15;
        int krow = isel[bh * TOPK + kc + row];
        float4 v = *(const float4*)(vf + ((size_t)bh * LKE + krow) * 64 + c4 * 4);
        T[row][c4 * 4 + 0] = v.x; T[row][c4 * 4 + 1] = v.y;
        T[row][c4 * 4 + 2] = v.z; T[row][c4 * 4 + 3] = v.w;
    }
    __syncthreads();
#pragma unroll
    for (int r = 0; r < 16; r++) {
        int f = r * 256 + t;
        int d = f >> 6, key = f & 63;
        vTh[(size_t)bh * 64 * TOPK + (size_t)d * TOPK + kc + key] = f2bf(T[key][d]);
    }
}

// ---------------- MFMA flash attention (single-bf16 P,V; f32 accum) ------------
// scores bounded in [-1,1] (q,k L2-normalized) -> no max subtraction needed.
__global__ __launch_bounds__(256) void attn_mfma_kernel(
    const unsigned short* __restrict__ qh,    // [BH][LQ][64] bf16
    const unsigned short* __restrict__ kselh, // [BH][512][64] bf16
    const unsigned short* __restrict__ vTh,   // [BH][64][512] bf16
    unsigned short* __restrict__ afT) {       // [b][LQ][512] bf16
    int bh = blockIdx.y, rt = blockIdx.x;
    int bq = bh >> 3, h = bh & 7;
    int t = threadIdx.x, w = t >> 6, lane = t & 63;
    __shared__ unsigned short Qs[64 * 64];
    __shared__ unsigned short Ks[64 * 64];
    __shared__ unsigned short Vts[64 * 64];
    __shared__ unsigned short Ps[4 * 16 * 64];

    const unsigned short* qb = qh + ((size_t)bh * LQ + (size_t)rt * 64) * 64;
    const unsigned short* kb = kselh + (size_t)bh * TOPK * 64;
    const unsigned short* vb = vTh + (size_t)bh * 64 * TOPK;

#pragma unroll
    for (int r = 0; r < 2; r++) {
        int c = r * 256 + t; int row = c >> 3, c8 = c & 7;
        bf16x8 v = *(const bf16x8*)(qb + row * 64 + c8 * 8);
        *(bf16x8*)((char*)Qs + ((row * 128 + c8 * 16) ^ ((row & 7) << 4))) = v;
    }
    auto stageKV = [&](int kc0) {
#pragma unroll
        for (int r = 0; r < 2; r++) {
            int c = r * 256 + t; int row = c >> 3, c8 = c & 7;
            int off = (row * 128 + c8 * 16) ^ ((row & 7) << 4);
            *(bf16x8*)((char*)Ks + off) = *(const bf16x8*)(kb + (kc0 + row) * 64 + c8 * 8);
            *(bf16x8*)((char*)Vts + off) = *(const bf16x8*)(vb + row * TOPK + kc0 + c8 * 8);
        }
    };
    stageKV(0);
    __syncthreads();

    bf16x8 qfrag[2];
#pragma unroll
    for (int kk = 0; kk < 2; kk++) {
        int row = w * 16 + (lane & 15);
        qfrag[kk] = *(const bf16x8*)((char*)Qs +
            ((row * 128 + kk * 64 + (lane >> 4) * 16) ^ ((row & 7) << 4)));
    }

    f32x4 o[4];
#pragma unroll
    for (int m = 0; m < 4; m++) o[m] = (f32x4){0.f, 0.f, 0.f, 0.f};
    float lsum[4] = {0.f, 0.f, 0.f, 0.f};
    unsigned short* pw = Ps + w * 16 * 64;

    for (int ch = 0; ch < 8; ch++) {
        f32x4 s[4];
#pragma unroll
        for (int n = 0; n < 4; n++) {
            s[n] = (f32x4){0.f, 0.f, 0.f, 0.f};
#pragma unroll
            for (int kk = 0; kk < 2; kk++) {
                int row = n * 16 + (lane & 15);
                bf16x8 kfr = *(const bf16x8*)((char*)Ks +
                    ((row * 128 + kk * 64 + (lane >> 4) * 16) ^ ((row & 7) << 4)));
                s[n] = mfma16(qfrag[kk], kfr, s[n]);
            }
        }
        float part[4] = {0.f, 0.f, 0.f, 0.f};
#pragma unroll
        for (int n = 0; n < 4; n++) {
#pragma unroll
            for (int rg = 0; rg < 4; rg++) {
                float p = __expf(s[n][rg]);
                part[rg] += p;
                int row = (lane >> 4) * 4 + rg, col = n * 16 + (lane & 15);
                *(unsigned short*)((char*)pw +
                    ((row * 128 + col * 2) ^ ((row & 7) << 4))) = f2bf(p);
            }
        }
#pragma unroll
        for (int rg = 0; rg < 4; rg++) {
            float v = part[rg];
            v += __shfl_xor(v, 1); v += __shfl_xor(v, 2);
            v += __shfl_xor(v, 4); v += __shfl_xor(v, 8);
            lsum[rg] += v;
        }
        bf16x8 pfrag[2];
#pragma unroll
        for (int kk = 0; kk < 2; kk++) {
            int row = lane & 15;
            pfrag[kk] = *(const bf16x8*)((char*)pw +
                ((row * 128 + kk * 64 + (lane >> 4) * 16) ^ ((row & 7) << 4)));
        }
#pragma unroll
        for (int m = 0; m < 4; m++) {
#pragma unroll
            for (int kk = 0; kk < 2; kk++) {
                int row = m * 16 + (lane & 15);
                bf16x8 vfr = *(const bf16x8*)((char*)Vts +
                    ((row * 128 + kk * 64 + (lane >> 4) * 16) ^ ((row & 7) << 4)));
                o[m] = mfma16(pfrag[kk], vfr, o[m]);
            }
        }
        if (ch < 7) {
            __syncthreads();
            stageKV((ch + 1) * 64);
            __syncthreads();
        }
    }
    int row0 = w * 16 + (lane >> 4) * 4;
#pragma unroll
    for (int rg = 0; rg < 4; rg++) {
        float invs = 1.0f / lsum[rg];
        int l = rt * 64 + row0 + rg;
        size_t base = ((size_t)bq * LQ + l) * 512 + h * 64 + (lane & 15);
#pragma unroll
        for (int m = 0; m < 4; m++)
            afT[base + m * 16] = f2bf(o[m][rg] * invs);
    }
}

// ---------------- per-location stats over 256 channels (pre is [b][l][256]) ----
__global__ void stats_loc_kernel(const float* __restrict__ pre, float* __restrict__ mu,
                                 float* __restrict__ rs) {
    int t = threadIdx.x;
    int grp = t >> 4, ln = t & 15;
    int loc = blockIdx.x * 16 + grp;
    const float4* p = (const float4*)(pre + (size_t)loc * 256);
    float s = 0.f, sq = 0.f;
#pragma unroll
    for (int i = 0; i < 4; i++) {
        float4 v = p[ln + i * 16];
        s += v.x + v.y + v.z + v.w;
        sq += v.x * v.x + v.y * v.y + v.z * v.z + v.w * v.w;
    }
#pragma unroll
    for (int d = 1; d < 16; d <<= 1) {
        s += __shfl_xor(s, d);
        sq += __shfl_xor(sq, d);
    }
    if (ln == 0) {
        float m = s * (1.0f / 256.0f);
        float var = fmaxf(sq * (1.0f / 256.0f) - m * m, 0.f);
        mu[loc] = m;
        rs[loc] = rsqrtf(var + 1e-5f);
    }
}

// ---------------- final LN + gamma*x + residual (transpose to [b][ch][l]) ------
__global__ __launch_bounds__(256) void final_kernel(
    const float* __restrict__ pre, const float* __restrict__ mu,
    const float* __restrict__ rs, const float* __restrict__ g,
    const float* __restrict__ beta, const float* __restrict__ gamma,
    const float* __restrict__ qs_in, float* __restrict__ out) {
    int lt = blockIdx.x, ot = blockIdx.y, b = blockIdx.z;
    int l0 = lt * 64, o0 = ot * 64;
    int t = threadIdx.x;
    __shared__ float T[64][65];
    float gm = gamma[0];
#pragma unroll
    for (int r = 0; r < 16; r++) {
        int f = r * 256 + t;
        int o = f & 63, l = f >> 6;
        int loc = b * LQ + l0 + l;
        float v = pre[(size_t)loc * 256 + o0 + o];
        T[o][l] = ((v - mu[loc]) * rs[loc] * g[o0 + o] + beta[o0 + o]) * gm;
    }
    __syncthreads();
#pragma unroll
    for (int r = 0; r < 16; r++) {
        int f = r * 256 + t;
        int l = f & 63, o = f >> 6;
        size_t oi = ((size_t)(b * DIMC + o0 + o)) * LQ + l0 + l;
        out[oi] = T[o][l] + qs_in[oi];
    }
}

extern "C" void kernel_launch(void* const* d_in, const int* in_sizes, int n_in,
                              void* d_out, int out_size, void* d_ws, size_t ws_size,
                              hipStream_t stream) {
    const float* qs_in = (const float*)d_in[0];
    const float* ctx   = (const float*)d_in[1];
    const int*   ridx  = (const int*)d_in[2];
    const float* g_ctx = (const float*)d_in[3];
    const float* b_ctx = (const float*)d_in[4];
    const float* g_qs  = (const float*)d_in[5];
    const float* b_qs  = (const float*)d_in[6];
    const float* w_kv  = (const float*)d_in[7];
    const float* w_q   = (const float*)d_in[8];
    const float* w_out = (const float*)d_in[9];
    const float* g_out = (const float*)d_in[10];
    const float* b_out = (const float*)d_in[11];
    const float* gamma = (const float*)d_in[12];
    float* out = (float*)d_out;

    char* ws = (char*)d_ws;
    size_t off = 0;
    auto alloc = [&](size_t bytes) { char* p = ws + off; off += (bytes + 255) & ~(size_t)255; return p; };

    float*          kf    = (float*)alloc((size_t)NBH * LKE * 64 * 4);
    float*          vf    = (float*)alloc((size_t)NBH * LKE * 64 * 4);
    unsigned*       kint  = (unsigned*)alloc((size_t)NBH * LKE * 64 * 4);
    unsigned short* qh    = (unsigned short*)alloc((size_t)NBH * LQ * 64 * 2);
    // union region: {ctxT_hi, ctxT_lo, qsT_hi} (early) / {afT} (late, after gemm<1>)
    char*           uni   = alloc((size_t)NB * LQ * INNER * 2);   // 33.6 MB
    unsigned short* ctxT_hi = (unsigned short*)(uni);
    unsigned short* ctxT_lo = (unsigned short*)(uni + (size_t)NB * LKE * DIMC * 2);
    unsigned short* qsT_hi  = (unsigned short*)(uni + (size_t)2 * NB * LKE * DIMC * 2);
    unsigned short* afT     = (unsigned short*)(uni);

    unsigned*       Qint  = (unsigned*)alloc((size_t)NBH * TOPK * 64 * 4);
    unsigned short* kselh = (unsigned short*)alloc((size_t)NBH * TOPK * 64 * 2);
    unsigned short* vTh   = (unsigned short*)alloc((size_t)NBH * 64 * TOPK * 2);
    float*          pre   = (float*)alloc((size_t)NB * LQ * DIMC * 4);
    unsigned*       min_d4= (unsigned*)alloc((size_t)4 * NBH * LKE * 4);
    float*          mu_c  = (float*)alloc(NB * LKE * 4);
    float*          rs_c  = (float*)alloc(NB * LKE * 4);
    float*          mu_q  = (float*)alloc(NB * LQ * 4);
    float*          rs_q  = (float*)alloc(NB * LQ * 4);
    float*          mu_o  = (float*)alloc(NB * LQ * 4);
    float*          rs_o  = (float*)alloc(NB * LQ * 4);
    int*            isel  = (int*)alloc(NBH * TOPK * 4);

    stats_kernel<<<(NB * LKE + 255) / 256, 256, 0, stream>>>(ctx, mu_c, rs_c, LKE, NB * LKE);
    stats_kernel<<<(NB * LQ + 255) / 256, 256, 0, stream>>>(qs_in, mu_q, rs_q, LQ, NB * LQ);
    ln_transpose_kernel<true><<<dim3(LKE / 64, DIMC / 64, NB), 256, 0, stream>>>(
        ctx, mu_c, rs_c, g_ctx, b_ctx, LKE, ctxT_hi, ctxT_lo);
    ln_transpose_kernel<false><<<dim3(LQ / 64, DIMC / 64, NB), 256, 0, stream>>>(
        qs_in, mu_q, rs_q, g_qs, b_qs, LQ, qsT_hi, nullptr);
    gemm_mfma_kernel<0><<<dim3(LKE / 128, 8, NB), 256, 0, stream>>>(
        w_kv, ctxT_hi, ctxT_lo, kf, vf, kint);
    gemm_mfma_kernel<1><<<dim3(LQ / 128, 4, NB), 256, 0, stream>>>(
        w_q, qsT_hi, qsT_hi, qh, nullptr, nullptr);
    qsample_kernel<<<dim3(TOPK / 64, NBH), 256, 0, stream>>>(
        qs_in, mu_q, rs_q, g_qs, b_qs, w_q, ridx, Qint);
    cdist_sad_kernel<<<dim3(LKE / 256, NBH, 4), 256, 0, stream>>>(kint, Qint, min_d4);
    select_topk_kernel<<<NBH, 256, 0, stream>>>(min_d4, isel);
    gather_k_kernel<<<(NBH * TOPK * 64) / 256, 256, 0, stream>>>(kf, isel, kselh);
    gather_vT_kernel<<<dim3(TOPK / 64, NBH), 256, 0, stream>>>(vf, isel, vTh);
    attn_mfma_kernel<<<dim3(LQ / 64, NBH), 256, 0, stream>>>(qh, kselh, vTh, afT);
    gemm_mfma_kernel<2><<<dim3(LQ / 128, 2, NB), 256, 0, stream>>>(
        w_out, afT, afT, pre, nullptr, nullptr);
    stats_loc_kernel<<<(NB * LQ) / 16, 256, 0, stream>>>(pre, mu_o, rs_o);
    final_kernel<<<dim3(LQ / 64, DIMC / 64, NB), 256, 0, stream>>>(
        pre, mu_o, rs_o, g_out, b_out, gamma, qs_in, out);
}